// Round 7
// baseline (506.354 us; speedup 1.0000x reference)
//
#include <hip/hip_runtime.h>

// GAT fused kernel for MI355X (gfx950) -- round 7.
// B=32768 graphs, N=14 nodes, F=C=128, E=64 edges (+14 self loops).
// Inputs f32 (edge_list int32); output f32: pred[32768] ++ attn[32768*196].
//
// R6 post-mortem: occupancy pinned at 16 waves/CU by UNIFIED VGPR+AGPR budget
// (~124/wave: arch 56 + AGPR acc ~68), not LDS. rocprof VGPR_Count hides AGPRs.
// R5 proved a 39-reg over-ask spills catastrophically; R3/R4/R6 all sit at
// 4 waves/SIMD & ~4000 cyc/graph/CU. This round: free ~16 regs by dropping the
// af1 register array (held across the rolled lr-loop) -- features staged into
// xg LDS (layer-uniform A-path) -- and target 5 waves/SIMD via
// __launch_bounds__(256,5) (budget 102/wave). Falsifier: WRITE_SIZE must stay
// ~25MB (no spill).

#define NEG_SLOPE 0.2f

typedef __bf16 bf16x8 __attribute__((ext_vector_type(8)));
typedef float f32x4 __attribute__((ext_vector_type(4)));
typedef unsigned short us4v __attribute__((ext_vector_type(4)));
typedef unsigned short us8v __attribute__((ext_vector_type(8)));

static __device__ __forceinline__ unsigned short f2bf(float f) {
  unsigned u = __builtin_bit_cast(unsigned, f);
  return (unsigned short)((u + 0x7FFFu + ((u >> 16) & 1u)) >> 16); // RNE, finite
}

// ---------------- setup: extended W frags (9 tiles) + weffc ----------------
// Frag slot s = ((lr*4+ks)*9+t)*64+lane, 8 shorts each.
// t<8 : B[k=ks*32+q*8+j][n=t*16+l] = W[k][n]
// t==8: l==0 -> (W@a_s)[k], l==1 -> (W@a_d)[k], else 0   (scores tile)
__global__ void gat_setup_kernel(const float* __restrict__ W1, const float* __restrict__ W2,
                                 const float* __restrict__ as1, const float* __restrict__ ad1,
                                 const float* __restrict__ as2, const float* __restrict__ ad2,
                                 const float* __restrict__ Wl, const float* __restrict__ bl,
                                 const float* __restrict__ Wp, const float* __restrict__ bp,
                                 unsigned short* __restrict__ wfrag, float* __restrict__ weffc) {
  const int blk = blockIdx.x, tid = threadIdx.x; // 19 blocks x 256
  if (blk < 18) {
    int slot = blk * 256 + tid;
    int lane = slot & 63, frag = slot >> 6;        // frag = lr*36 + ks*9 + t
    int lr = frag / 36, rem = frag % 36, ks = rem / 9, t = rem % 9;
    const float* W = lr ? W2 : W1;
    int q = lane >> 4, l = lane & 15;
    int k0 = ks * 32 + q * 8;
    us8v hv;
    if (t < 8) {
      int n = t * 16 + l;
      #pragma unroll
      for (int j = 0; j < 8; ++j) hv[j] = f2bf(W[(k0 + j) * 128 + n]);
    } else {
      const float* vec = l ? (lr ? ad2 : ad1) : (lr ? as2 : as1);
      #pragma unroll
      for (int j = 0; j < 8; ++j) {
        float s = 0.f;
        if (l < 2) {
          const float* wr = W + (size_t)(k0 + j) * 128;
          for (int c = 0; c < 128; ++c) s += wr[c] * vec[c];
        }
        hv[j] = f2bf(s);
      }
    }
    *(us8v*)(wfrag + slot * 8) = hv;
  } else {
    // weffc[(t*64+lane)*4+r] = (4q+r)<14 ? sum_c Wl[((4q+r)*128+t*16+l)*64+c]*Wp[c] : 0
    for (int i = tid; i < 2048; i += 256) {
      int r = i & 3, lane = (i >> 2) & 63, t = i >> 8;
      int q = lane >> 4, l = lane & 15;
      int row = 4 * q + r, col = t * 16 + l;
      float s = 0.f;
      if (row < 14) {
        const float* wl = Wl + (size_t)(row * 128 + col) * 64;
        #pragma unroll 8
        for (int c = 0; c < 64; ++c) s += wl[c] * Wp[c];
      }
      weffc[i] = s;
    }
    if (tid == 0) {
      float s = 0.f;
      for (int c = 0; c < 64; ++c) s += bl[c] * Wp[c];
      weffc[2048] = s + bp[0];
    }
  }
}

// Wave-private LDS scratch, 5632 B. 4 waves -> 22,528 B/block.
struct __align__(16) WaveLds {
  unsigned short xh[2176]; // xg[16][136] (A-op, both layers) UNION ht[128][16] (P@h B-op)
  float Pf[256];           // unnormalized P f32 [16][16] [dst][src] (atomicAdd)
  float asn[16], adn[16], mz[16];
  int emask[16];           // per-src bitmask of existing dsts
};

__global__ __launch_bounds__(256, 5) void gat_kernel(
    const float* __restrict__ feat, const int* __restrict__ edges,
    const float* __restrict__ b1v, const float* __restrict__ b2v,
    const unsigned short* __restrict__ wfrag, const float* __restrict__ weffc,
    float* __restrict__ out) {
  __shared__ WaveLds wls[4];
  const int tid = threadIdx.x;
  const int wave = tid >> 6, lane = tid & 63;
  const int q = lane >> 4, l = lane & 15;
  const int g = blockIdx.x * 4 + wave;
  WaveLds& S = wls[wave];

  us8v z8v = {0, 0, 0, 0, 0, 0, 0, 0};
  const bf16x8 zf = __builtin_bit_cast(bf16x8, z8v);

  // ---- stage feature (f32 -> bf16) -> xg[16][136]; zero rows 14..15 ----
  {
    const float* fb = feat + (size_t)g * 1792;
    for (int i = lane; i < 448; i += 64) { // 7 iters, 16B/lane coalesced
      f32x4 v = *(const f32x4*)(fb + i * 4);
      us4v hv;
      hv[0] = f2bf(v[0]); hv[1] = f2bf(v[1]); hv[2] = f2bf(v[2]); hv[3] = f2bf(v[3]);
      int row = i >> 5, col = (i & 31) << 2;
      *(us4v*)(&S.xh[row * 136 + col]) = hv;
    }
    if (lane < 32) {
      int row = 14 + (lane >> 4), c8 = (lane & 15) << 3;
      *(us8v*)(&S.xh[row * 136 + c8]) = z8v;
    }
  }
  // edge endpoints, one edge per lane (E=64)
  int esrc, edst;
  { const int2 e2 = *(const int2*)(edges + (size_t)g * 128 + lane * 2); esrc = e2.x; edst = e2.y; }
  if (lane < 16) S.emask[lane] = 0;
  __threadfence_block();

  f32x4 oacc[8];

  for (int lr = 0; lr < 2; ++lr) {
    const float* bsv = lr ? b2v : b1v;

    // ---- h = x@W + scores tile (M=16, 9 N-tiles, 4 K-steps) ----
    // A from xg LDS (uniform both layers); B-frags streamed from L2.
    f32x4 hacc[9];
    #pragma unroll
    for (int t = 0; t < 9; ++t) hacc[t] = (f32x4){0.f, 0.f, 0.f, 0.f};
    #pragma unroll
    for (int ks = 0; ks < 4; ++ks) {
      bf16x8 af = *(const bf16x8*)(&S.xh[l * 136 + ks * 32 + q * 8]); // ds_read_b128
      const unsigned short* wk = wfrag + ((lr * 4 + ks) * 9) * 512 + lane * 8;
      #pragma unroll
      for (int t = 0; t < 8; ++t) {
        bf16x8 bfv = *(const bf16x8*)(wk + t * 512); // 16B/lane, L2-hot
        hacc[t] = __builtin_amdgcn_mfma_f32_16x16x32_bf16(af, bfv, hacc[t], 0, 0, 0);
      }
      bf16x8 bsc = (l < 2) ? *(const bf16x8*)(wk + 8 * 512) : zf; // scores tile (cols 0,1)
      hacc[8] = __builtin_amdgcn_mfma_f32_16x16x32_bf16(af, bsc, hacc[8], 0, 0, 0);
    }

    // ---- scores straight out of hacc[8]: D[row=4q+r][col=l], l=0->as, l=1->ad ----
    if (l < 2) {
      float* dst = l ? S.adn : S.asn;
      *(f32x4*)(dst + 4 * q) = hacc[8];
    }

    // ---- h -> ht[128][16] bf16 (B-op of P@h): ht[col][node]; xg now dead ----
    #pragma unroll
    for (int t = 0; t < 8; ++t) {
      us4v hv;
      hv[0] = f2bf(hacc[t][0]); hv[1] = f2bf(hacc[t][1]);
      hv[2] = f2bf(hacc[t][2]); hv[3] = f2bf(hacc[t][3]);
      *(us4v*)(&S.xh[(t * 16 + l) * 16 + q * 4]) = hv;
    }
    *(f32x4*)(&S.Pf[lane * 4]) = (f32x4){0.f, 0.f, 0.f, 0.f}; // all 256 zeroed
    __threadfence_block();

    // ---- edges: ev = exp(leaky(asn[src]+adn[dst])); accumulate unnormalized P ----
    float f0 = S.asn[esrc] + S.adn[edst];
    float ev = __expf(f0 > 0.f ? f0 : NEG_SLOPE * f0);
    atomicAdd(&S.Pf[edst * 16 + esrc], ev);
    if (lr == 0) atomicOr(&S.emask[esrc], 1 << edst);
    if (lane < 14) { // self loops
      float f2 = S.asn[lane] + S.adn[lane];
      atomicAdd(&S.Pf[lane * 17], __expf(f2 > 0.f ? f2 : NEG_SLOPE * f2));
      if (lr == 0) atomicOr(&S.emask[lane], 1 << lane);
    }
    __threadfence_block();

    // ---- per-dst 1/z; mz[14..15]=0 kills pad rows in P@h ----
    if (lane < 16) {
      f32x4 s0 = *(const f32x4*)(&S.Pf[lane * 16]) + *(const f32x4*)(&S.Pf[lane * 16 + 4]) +
                 *(const f32x4*)(&S.Pf[lane * 16 + 8]) + *(const f32x4*)(&S.Pf[lane * 16 + 12]);
      float z = s0[0] + s0[1] + s0[2] + s0[3];
      S.mz[lane] = (lane < 14) ? 1.f / z : 0.f;
    }
    __threadfence_block();

    // ---- out = P @ h + b; A-frag = bf16(Pf[l][8q+j] * mz[l]) ----
    #pragma unroll
    for (int t = 0; t < 8; ++t) {
      float bb = bsv[t * 16 + l];
      oacc[t] = (f32x4){bb, bb, bb, bb};
    }
    bf16x8 paf = zf;
    if (q < 2) {
      f32x4 p0 = *(const f32x4*)(&S.Pf[l * 16 + q * 8]);
      f32x4 p1 = *(const f32x4*)(&S.Pf[l * 16 + q * 8 + 4]);
      float m = S.mz[l];
      us8v pv;
      pv[0] = f2bf(p0[0] * m); pv[1] = f2bf(p0[1] * m);
      pv[2] = f2bf(p0[2] * m); pv[3] = f2bf(p0[3] * m);
      pv[4] = f2bf(p1[0] * m); pv[5] = f2bf(p1[1] * m);
      pv[6] = f2bf(p1[2] * m); pv[7] = f2bf(p1[3] * m);
      paf = __builtin_bit_cast(bf16x8, pv);
    }
    #pragma unroll
    for (int t = 0; t < 8; ++t) {
      bf16x8 hbf = (q < 2) ? *(const bf16x8*)(&S.xh[(t * 16 + l) * 16 + q * 8]) : zf;
      oacc[t] = __builtin_amdgcn_mfma_f32_16x16x32_bf16(paf, hbf, oacc[t], 0, 0, 0);
    }

    if (lr == 0) {
      // x2 = relu(out1) -> xg[16][136] for layer-2 A-op (ht consumed above)
      __threadfence_block();
      #pragma unroll
      for (int t = 0; t < 8; ++t) {
        #pragma unroll
        for (int r = 0; r < 4; ++r) {
          float v = fmaxf(oacc[t][r], 0.f);
          S.xh[(4 * q + r) * 136 + t * 16 + l] = f2bf(v);
        }
      }
      __threadfence_block();
    }
  }

  // ---- pred = sigmoid(sum oacc .* weffc + beff); weffc pre-masked rows>=14 ----
  float part = 0.f;
  #pragma unroll
  for (int t = 0; t < 8; ++t) {
    f32x4 wv = *(const f32x4*)(weffc + t * 256 + lane * 4); // L1/L2-hot
    part += oacc[t][0] * wv[0] + oacc[t][1] * wv[1] + oacc[t][2] * wv[2] + oacc[t][3] * wv[3];
  }
  #pragma unroll
  for (int m = 1; m < 64; m <<= 1) part += __shfl_xor(part, m, 64);
  if (lane == 0) out[g] = 1.f / (1.f + __expf(-(part + weffc[2048])));

  // ---- attn flush: alpha recomputed from layer-2 asn/adn/mz + emask ----
  {
    float* oa = out + 32768 + (size_t)g * 196;
    #pragma unroll
    for (int k = 0; k < 4; ++k) {
      int i = lane + k * 64;
      if (i < 196) {
        int s = (i * 4682) >> 16; // floor(i/14) for i in [0,196)
        int d = i - s * 14;
        float a = 0.f;
        if ((S.emask[s] >> d) & 1) {
          float f = S.asn[s] + S.adn[d];
          a = __expf(f > 0.f ? f : NEG_SLOPE * f) * S.mz[d];
        }
        oa[i] = a;
      }
    }
  }
}

extern "C" void kernel_launch(void* const* d_in, const int* in_sizes, int n_in,
                              void* d_out, int out_size, void* d_ws, size_t ws_size,
                              hipStream_t stream) {
  const float* feat = (const float*)d_in[0];
  const int* edges = (const int*)d_in[1];
  const float* W1 = (const float*)d_in[2];
  const float* as1 = (const float*)d_in[3];
  const float* ad1 = (const float*)d_in[4];
  const float* b1 = (const float*)d_in[5];
  const float* W2 = (const float*)d_in[6];
  const float* as2 = (const float*)d_in[7];
  const float* ad2 = (const float*)d_in[8];
  const float* b2 = (const float*)d_in[9];
  const float* Wl = (const float*)d_in[10];
  const float* bl = (const float*)d_in[11];
  const float* Wp = (const float*)d_in[12];
  const float* bp = (const float*)d_in[13];

  unsigned short* wfrag = (unsigned short*)d_ws;          // 73,728 B (72 frags)
  float* weffc = (float*)((char*)d_ws + 73728);           // 2049 f32

  gat_setup_kernel<<<19, 256, 0, stream>>>(W1, W2, as1, ad1, as2, ad2,
                                           Wl, bl, Wp, bp, wfrag, weffc);
  gat_kernel<<<8192, 256, 0, stream>>>(feat, edges, b1, b2, wfrag, weffc,
                                       (float*)d_out);
}